// Round 7
// baseline (372.991 us; speedup 1.0000x reference)
//
#include <hip/hip_runtime.h>
#include <math.h>

typedef _Float16 half8 __attribute__((ext_vector_type(8)));
typedef _Float16 half4 __attribute__((ext_vector_type(4)));
typedef float f32x4 __attribute__((ext_vector_type(4)));

#define NPTS 262144
#define BM 128
#define NTHREADS 512

// ws layout in SHORT (fp16) elements, row-major [out][Kpad], 16B-aligned.
#define W0_OFF 0        // [256][64]   (K=60 padded to 64)
#define W1_OFF 16384    // [256][256]
#define W2_OFF 81920    // [256][320]  (cols 0..255 h-part, 256..315 x-part, 316..319 zero)
#define W3_OFF 163840   // [256][256]
#define WH_OFF 229376   // [16][256]   (rows: 0-2 xyz, 3-6 rot, 7-9 scale, 10 op, 11-15 zero)

__device__ __forceinline__ short f2h(float f) {
  _Float16 h = (_Float16)f;
  return __builtin_bit_cast(short, h);
}

__global__ void prep_kernel(const float* __restrict__ W0, const float* __restrict__ W1,
                            const float* __restrict__ W2, const float* __restrict__ W3,
                            const float* __restrict__ Wxyz, const float* __restrict__ Wrot,
                            const float* __restrict__ Wscale, const float* __restrict__ Wop,
                            short* __restrict__ ws) {
  const int stride = gridDim.x * blockDim.x;
  const int t0 = blockIdx.x * blockDim.x + threadIdx.x;
  for (int i = t0; i < 256 * 64; i += stride) {
    const int j = i >> 6, k = i & 63;
    ws[W0_OFF + i] = (k < 60) ? f2h(W0[j * 60 + k]) : (short)0;
  }
  for (int i = t0; i < 256 * 256; i += stride) ws[W1_OFF + i] = f2h(W1[i]);
  for (int i = t0; i < 256 * 320; i += stride) {
    const int j = i / 320, k = i - j * 320;
    ws[W2_OFF + i] = (k < 316) ? f2h(W2[j * 316 + k]) : (short)0;
  }
  for (int i = t0; i < 256 * 256; i += stride) ws[W3_OFF + i] = f2h(W3[i]);
  for (int i = t0; i < 16 * 256; i += stride) {
    const int j = i >> 8, k = i & 255;
    float v = 0.0f;
    if (j < 3) v = Wxyz[j * 256 + k];
    else if (j < 7) v = Wrot[(j - 3) * 256 + k];
    else if (j < 10) v = Wscale[(j - 7) * 256 + k];
    else if (j == 10) v = Wop[k];
    ws[WH_OFF + i] = f2h(v);
  }
}

// A-fragment: weight rows (first MFMA operand). lane holds row=lr, k=lk*8+[0..7].
__device__ __forceinline__ void load_a(half8 (&dst)[4], const short* const (&wrow)[4], int koff) {
#pragma unroll
  for (int x = 0; x < 4; ++x) dst[x] = *(const half8*)(wrow[x] + koff);
}

// B-fragment: activations from swizzled LDS. lane holds col m (=lr), k=lk*8+[0..7].
__device__ __forceinline__ void load_b(half8 (&dst)[4], const char* Ab, int Astride,
                                       int kbyte, int pg, int lr) {
#pragma unroll
  for (int x = 0; x < 4; ++x) {
    const int m = pg * 64 + x * 16 + lr;
    dst[x] = *(const half8*)(Ab + ((m * Astride + kbyte) ^ ((m & 7) << 4)));
  }
}

// acc[jt][mt] += W-tile * act-tile over NK k-steps of 32.
// Wb: global fp16 weights [256][Kpad] row-major; activations in swizzled LDS.
template <int NK>
__device__ __forceinline__ void gemm_phase(f32x4 (&acc)[4][4],
                                           const char* Ab, int Astride,
                                           const short* __restrict__ Wb, int Kpad, int Wkoff,
                                           int fg, int pg, int lr, int lk) {
  half8 a[3][4], b[2][4];
  const short* wrow[4];
#pragma unroll
  for (int x = 0; x < 4; ++x)
    wrow[x] = Wb + (fg * 64 + x * 16 + lr) * Kpad + Wkoff + lk * 8;
  load_a(a[0], wrow, 0);
  if (NK > 1) load_a(a[1], wrow, 32);
  load_b(b[0], Ab, Astride, lk * 16, pg, lr);
#pragma unroll
  for (int ks = 0; ks < NK; ++ks) {
    if (ks + 2 < NK) load_a(a[(ks + 2) % 3], wrow, (ks + 2) * 32);
    if (ks + 1 < NK) load_b(b[(ks + 1) & 1], Ab, Astride, (ks + 1) * 64 + lk * 16, pg, lr);
#pragma unroll
    for (int jt = 0; jt < 4; ++jt)
#pragma unroll
      for (int mt = 0; mt < 4; ++mt)
        acc[jt][mt] = __builtin_amdgcn_mfma_f32_16x16x32_f16(a[ks % 3][jt], b[ks & 1][mt],
                                                             acc[jt][mt], 0, 0, 0);
  }
}

__device__ __forceinline__ void zero_acc(f32x4 (&acc)[4][4]) {
#pragma unroll
  for (int jt = 0; jt < 4; ++jt)
#pragma unroll
    for (int mt = 0; mt < 4; ++mt) {
      f32x4 z = {0.f, 0.f, 0.f, 0.f};
      acc[jt][mt] = z;
    }
}

// bias + relu + fp16 pack: lane holds D[j=fg*64+jt*16+lk*4+r][m=pg*64+mt*16+lr]
// -> one 8B ds_write per tile (4 consecutive out-features of one point).
__device__ __forceinline__ void epilogue(f32x4 (&acc)[4][4], const float* __restrict__ bias,
                                         char* dst, int fg, int pg, int lr, int lk) {
#pragma unroll
  for (int jt = 0; jt < 4; ++jt) {
    const int j0 = fg * 64 + jt * 16 + lk * 4;
    const f32x4 bv = *(const f32x4*)(bias + j0);
#pragma unroll
    for (int mt = 0; mt < 4; ++mt) {
      const int m = pg * 64 + mt * 16 + lr;
      half4 hv;
#pragma unroll
      for (int r = 0; r < 4; ++r) hv[r] = (_Float16)fmaxf(acc[jt][mt][r] + bv[r], 0.f);
      *(half4*)(dst + ((m * 512 + j0 * 2) ^ ((m & 7) << 4))) = hv;
    }
  }
}

__global__ __launch_bounds__(NTHREADS, 2) void deform_kernel(
    const float* __restrict__ xyz, const float* __restrict__ tptr,
    const float* __restrict__ b0, const float* __restrict__ b1,
    const float* __restrict__ b2, const float* __restrict__ b3,
    const float* __restrict__ bxyz, const float* __restrict__ brot,
    const float* __restrict__ bscale, const float* __restrict__ bop,
    const short* __restrict__ ws, float* __restrict__ out) {
  __shared__ short xin[BM * 64];    // fp16 [128][64], stride 128B, XOR-swizzled; 16 KB
  __shared__ short hbuf[BM * 256];  // fp16 [128][256], stride 512B, XOR-swizzled; 64 KB

  const int t = threadIdx.x;
  const int lane = t & 63;
  const int wid = t >> 6;
  const int fg = wid & 3;   // feature group: 64 out-features
  const int pg = wid >> 2;  // point group: 64 points
  const int lr = lane & 15;
  const int lk = lane >> 4;
  const int p0 = blockIdx.x * BM;

  const float tval = tptr[0];

  // ---- encoding: thread t fills point m = t>>2, d-slots [q*16, q*16+16) ----
  {
    const int m = t >> 2, q = t & 3;
    const int p = p0 + m;
    const float xc[3] = {xyz[p * 3 + 0], xyz[p * 3 + 1], xyz[p * 3 + 2]};
    half8 v0, v1;
#pragma unroll
    for (int dd = 0; dd < 16; ++dd) {
      const int d = q * 16 + dd;
      float v;
      if (d < 3) {
        v = xc[d];
      } else if (d < 39) {
        const int idx = d - 3;
        const int c = idx / 12;
        const int r = idx - c * 12;
        const int e = (r >= 6) ? r - 6 : r;
        const float rev = xc[c] * (0.5f * (float)(1 << e));  // x*2^e*pi = 2pi * rev
        const float fr = rev - floorf(rev);
        v = (r < 6) ? __builtin_amdgcn_sinf(fr) : __builtin_amdgcn_cosf(fr);
      } else if (d == 39) {
        v = tval;
      } else if (d < 60) {
        const int r = d - 40;
        const int e = (r >= 10) ? r - 10 : r;
        const float rev = tval * (0.5f * (float)(1 << e));
        const float fr = rev - floorf(rev);
        v = (r < 10) ? __builtin_amdgcn_sinf(fr) : __builtin_amdgcn_cosf(fr);
      } else {
        v = 0.f;
      }
      const _Float16 hv = (_Float16)v;
      if (dd < 8) v0[dd] = hv; else v1[dd - 8] = hv;
    }
    char* base = (char*)xin;
    *(half8*)(base + ((m * 128 + q * 32) ^ ((m & 7) << 4))) = v0;
    *(half8*)(base + ((m * 128 + q * 32 + 16) ^ ((m & 7) << 4))) = v1;
  }
  __syncthreads();

  f32x4 acc[4][4];

  // layer 0: xin (K=64) ; writes hbuf (first touch, no hazard)
  zero_acc(acc);
  gemm_phase<2>(acc, (const char*)xin, 128, ws + W0_OFF, 64, 0, fg, pg, lr, lk);
  epilogue(acc, b0, (char*)hbuf, fg, pg, lr, lk);
  __syncthreads();

  // layer 1: hbuf (K=256), in-place
  zero_acc(acc);
  gemm_phase<8>(acc, (const char*)hbuf, 512, ws + W1_OFF, 256, 0, fg, pg, lr, lk);
  __syncthreads();  // all reads done
  epilogue(acc, b1, (char*)hbuf, fg, pg, lr, lk);
  __syncthreads();

  // layer 2 (skip): [hbuf | xin] (K=256+64), in-place
  zero_acc(acc);
  gemm_phase<8>(acc, (const char*)hbuf, 512, ws + W2_OFF, 320, 0, fg, pg, lr, lk);
  gemm_phase<2>(acc, (const char*)xin, 128, ws + W2_OFF, 320, 256, fg, pg, lr, lk);
  __syncthreads();
  epilogue(acc, b2, (char*)hbuf, fg, pg, lr, lk);
  __syncthreads();

  // layer 3: hbuf (K=256), in-place
  zero_acc(acc);
  gemm_phase<8>(acc, (const char*)hbuf, 512, ws + W3_OFF, 256, 0, fg, pg, lr, lk);
  __syncthreads();
  epilogue(acc, b3, (char*)hbuf, fg, pg, lr, lk);
  __syncthreads();

  // ---- heads: WH[16][256] @ h3 ; fg==0 waves cover all 128 points ----
  if (fg == 0) {
    f32x4 hacc[4];
#pragma unroll
    for (int mt = 0; mt < 4; ++mt) {
      f32x4 z = {0.f, 0.f, 0.f, 0.f};
      hacc[mt] = z;
    }
    const short* WH = ws + WH_OFF;
#pragma unroll
    for (int ks = 0; ks < 8; ++ks) {
      const half8 ah = *(const half8*)(WH + lr * 256 + ks * 32 + lk * 8);
#pragma unroll
      for (int mt = 0; mt < 4; ++mt) {
        const int m = pg * 64 + mt * 16 + lr;
        const half8 bh = *(const half8*)((const char*)hbuf +
                                         ((m * 512 + ks * 64 + lk * 16) ^ ((m & 7) << 4)));
        hacc[mt] = __builtin_amdgcn_mfma_f32_16x16x32_f16(ah, bh, hacc[mt], 0, 0, 0);
      }
    }
    // lane holds D[j = lk*4 + r][m = pg*64 + mt*16 + lr]
    float hb[4];
#pragma unroll
    for (int r = 0; r < 4; ++r) {
      const int j = lk * 4 + r;
      hb[r] = (j < 3) ? bxyz[j] : (j < 7) ? brot[j - 3] : (j < 10) ? bscale[j - 7]
              : (j == 10) ? bop[0] : 0.f;
    }
#pragma unroll
    for (int mt = 0; mt < 4; ++mt) {
      const int p = p0 + pg * 64 + mt * 16 + lr;
#pragma unroll
      for (int r = 0; r < 4; ++r) {
        const int j = lk * 4 + r;
        const float v = hacc[mt][r] + hb[r];
        if (j < 3)        out[p * 3 + j] = v;
        else if (j < 7)   out[3 * NPTS + p * 4 + (j - 3)] = v;
        else if (j < 10)  out[7 * NPTS + p * 3 + (j - 7)] = v;
        else if (j == 10) out[10 * NPTS + p] = v;
      }
    }
  }
}

extern "C" void kernel_launch(void* const* d_in, const int* in_sizes, int n_in,
                              void* d_out, int out_size, void* d_ws, size_t ws_size,
                              hipStream_t stream) {
  const float* xyz    = (const float*)d_in[0];
  const float* tptr   = (const float*)d_in[1];
  const float* W0     = (const float*)d_in[2];
  const float* b0     = (const float*)d_in[3];
  const float* W1     = (const float*)d_in[4];
  const float* b1     = (const float*)d_in[5];
  const float* W2     = (const float*)d_in[6];
  const float* b2     = (const float*)d_in[7];
  const float* W3     = (const float*)d_in[8];
  const float* b3     = (const float*)d_in[9];
  const float* Wxyz   = (const float*)d_in[10];
  const float* bxyz   = (const float*)d_in[11];
  const float* Wrot   = (const float*)d_in[12];
  const float* brot   = (const float*)d_in[13];
  const float* Wscale = (const float*)d_in[14];
  const float* bscale = (const float*)d_in[15];
  const float* Wop    = (const float*)d_in[16];
  const float* bop    = (const float*)d_in[17];
  short* ws  = (short*)d_ws;
  float* out = (float*)d_out;

  prep_kernel<<<256, 256, 0, stream>>>(W0, W1, W2, W3, Wxyz, Wrot, Wscale, Wop, ws);
  deform_kernel<<<NPTS / BM, NTHREADS, 0, stream>>>(xyz, tptr, b0, b1, b2, b3,
                                                    bxyz, brot, bscale, bop, ws, out);
}

// Round 8
// 246.178 us; speedup vs baseline: 1.5151x; 1.5151x over previous
//
#include <hip/hip_runtime.h>
#include <math.h>

typedef _Float16 half8 __attribute__((ext_vector_type(8)));
typedef _Float16 half4 __attribute__((ext_vector_type(4)));
typedef float f32x4 __attribute__((ext_vector_type(4)));

#define NPTS 262144
#define BM 128
#define NTHREADS 512

// ws layout (shorts): 14 chunk images of [256 rows][64 k] fp16 (32 KB each),
// XOR-swizzled within each 128B row (short idx: kk ^ ((r&7)<<3)), contiguous;
// then WH [16][256] row-major.
// Chunk stream: c0=W0(k0..63) | c1..4=W1 | c5..8=W2 h-part | c9=W2 x-part | c10..13=W3.
#define CHUNK_SHORTS 16384
#define WH_OFF (14 * CHUNK_SHORTS)

typedef const __attribute__((address_space(1))) void g_void_t;
typedef __attribute__((address_space(3))) void l_void_t;

__device__ __forceinline__ short f2h(float f) {
  _Float16 h = (_Float16)f;
  return __builtin_bit_cast(short, h);
}

__global__ void prep_kernel(const float* __restrict__ W0, const float* __restrict__ W1,
                            const float* __restrict__ W2, const float* __restrict__ W3,
                            const float* __restrict__ Wxyz, const float* __restrict__ Wrot,
                            const float* __restrict__ Wscale, const float* __restrict__ Wop,
                            short* __restrict__ ws) {
  const int stride = gridDim.x * blockDim.x;
  const int t0 = blockIdx.x * blockDim.x + threadIdx.x;
  for (int i = t0; i < 14 * CHUNK_SHORTS; i += stride) {
    const int c = i >> 14;
    const int r = (i >> 6) & 255;
    const int kk = i & 63;
    float v = 0.0f;
    if (c == 0)      { if (kk < 60) v = W0[r * 60 + kk]; }
    else if (c <= 4) { v = W1[r * 256 + (c - 1) * 64 + kk]; }
    else if (c <= 8) { v = W2[r * 316 + (c - 5) * 64 + kk]; }
    else if (c == 9) { if (kk < 60) v = W2[r * 316 + 256 + kk]; }
    else             { v = W3[r * 256 + (c - 10) * 64 + kk]; }
    ws[c * CHUNK_SHORTS + r * 64 + (kk ^ ((r & 7) << 3))] = f2h(v);
  }
  for (int i = t0; i < 16 * 256; i += stride) {
    const int j = i >> 8, k = i & 255;
    float v = 0.0f;
    if (j < 3) v = Wxyz[j * 256 + k];
    else if (j < 7) v = Wrot[(j - 3) * 256 + k];
    else if (j < 10) v = Wscale[(j - 7) * 256 + k];
    else if (j == 10) v = Wop[k];
    ws[WH_OFF + i] = f2h(v);
  }
}

// Async-copy one 32KB chunk image (already swizzled in global) linearly into LDS.
__device__ __forceinline__ void stage_chunk(const short* __restrict__ ws, int c,
                                            short* dst, int t) {
  const char* src = (const char*)(ws + c * CHUNK_SHORTS);
  char* d = (char*)dst;
  const int wave = t >> 6;
  const int lane = t & 63;
#pragma unroll
  for (int r = 0; r < 4; ++r) {
    const int off = r * 8192 + wave * 1024;
    __builtin_amdgcn_global_load_lds((g_void_t*)(src + off + lane * 16),
                                     (l_void_t*)(d + off), 16, 0, 0);
  }
}

// One 64-k chunk: acc[jt][mt] += W-tile(LDS) * act-tile(LDS). 16 ds_read_b128 + 32 MFMA.
__device__ __forceinline__ void compute_chunk(f32x4 (&acc)[4][4],
                                              const short* wb,
                                              const char* bsrc, int bstride, int bkbase,
                                              int fg, int pg, int lr, int lk) {
  half8 a[2][4], b[2][4];
#pragma unroll
  for (int ks = 0; ks < 2; ++ks) {
#pragma unroll
    for (int x = 0; x < 4; ++x) {
      const int row = fg * 64 + x * 16 + lr;
      a[ks][x] = *(const half8*)((const char*)wb + row * 128 +
                                 ((ks * 64 + lk * 16) ^ ((row & 7) << 4)));
      const int m = pg * 64 + x * 16 + lr;
      b[ks][x] = *(const half8*)(bsrc + m * bstride +
                                 ((bkbase + ks * 64 + lk * 16) ^ ((m & 7) << 4)));
    }
  }
#pragma unroll
  for (int ks = 0; ks < 2; ++ks)
#pragma unroll
    for (int jt = 0; jt < 4; ++jt)
#pragma unroll
      for (int mt = 0; mt < 4; ++mt)
        acc[jt][mt] = __builtin_amdgcn_mfma_f32_16x16x32_f16(a[ks][jt], b[ks][mt],
                                                             acc[jt][mt], 0, 0, 0);
}

__device__ __forceinline__ void zero_acc(f32x4 (&acc)[4][4]) {
#pragma unroll
  for (int jt = 0; jt < 4; ++jt)
#pragma unroll
    for (int mt = 0; mt < 4; ++mt) {
      f32x4 z = {0.f, 0.f, 0.f, 0.f};
      acc[jt][mt] = z;
    }
}

// bias + relu + fp16 pack: lane holds D[j=fg*64+jt*16+lk*4+r][m=pg*64+mt*16+lr].
__device__ __forceinline__ void epilogue(f32x4 (&acc)[4][4], const float* __restrict__ bias,
                                         char* dst, int fg, int pg, int lr, int lk) {
#pragma unroll
  for (int jt = 0; jt < 4; ++jt) {
    const int j0 = fg * 64 + jt * 16 + lk * 4;
    const f32x4 bv = *(const f32x4*)(bias + j0);
#pragma unroll
    for (int mt = 0; mt < 4; ++mt) {
      const int m = pg * 64 + mt * 16 + lr;
      half4 hv;
#pragma unroll
      for (int r = 0; r < 4; ++r) hv[r] = (_Float16)fmaxf(acc[jt][mt][r] + bv[r], 0.f);
      *(half4*)(dst + ((m * 512 + j0 * 2) ^ ((m & 7) << 4))) = hv;
    }
  }
}

__global__ __launch_bounds__(NTHREADS, 2) void deform_kernel(
    const float* __restrict__ xyz, const float* __restrict__ tptr,
    const float* __restrict__ b0, const float* __restrict__ b1,
    const float* __restrict__ b2, const float* __restrict__ b3,
    const float* __restrict__ bxyz, const float* __restrict__ brot,
    const float* __restrict__ bscale, const float* __restrict__ bop,
    const short* __restrict__ ws, float* __restrict__ out) {
  __shared__ short xin[BM * 64];           // 16 KB, stride 128B, XOR-swizzled
  __shared__ short hbuf[BM * 256];         // 64 KB, stride 512B, XOR-swizzled
  __shared__ short wbuf[2][CHUNK_SHORTS];  // 2 x 32 KB double-buffered weight chunks

  const int t = threadIdx.x;
  const int lane = t & 63;
  const int wid = t >> 6;
  const int fg = wid & 3;
  const int pg = wid >> 2;
  const int lr = lane & 15;
  const int lk = lane >> 4;
  const int p0 = blockIdx.x * BM;

  const float tval = tptr[0];

  // ---- encoding: thread t fills point m = t>>2, d-slots [q*16, q*16+16) ----
  {
    const int m = t >> 2, q = t & 3;
    const int p = p0 + m;
    const float xc[3] = {xyz[p * 3 + 0], xyz[p * 3 + 1], xyz[p * 3 + 2]};
    half8 v0, v1;
#pragma unroll
    for (int dd = 0; dd < 16; ++dd) {
      const int d = q * 16 + dd;
      float v;
      if (d < 3) {
        v = xc[d];
      } else if (d < 39) {
        const int idx = d - 3;
        const int c = idx / 12;
        const int r = idx - c * 12;
        const int e = (r >= 6) ? r - 6 : r;
        const float rev = xc[c] * (0.5f * (float)(1 << e));
        const float fr = rev - floorf(rev);
        v = (r < 6) ? __builtin_amdgcn_sinf(fr) : __builtin_amdgcn_cosf(fr);
      } else if (d == 39) {
        v = tval;
      } else if (d < 60) {
        const int r = d - 40;
        const int e = (r >= 10) ? r - 10 : r;
        const float rev = tval * (0.5f * (float)(1 << e));
        const float fr = rev - floorf(rev);
        v = (r < 10) ? __builtin_amdgcn_sinf(fr) : __builtin_amdgcn_cosf(fr);
      } else {
        v = 0.f;
      }
      const _Float16 hv = (_Float16)v;
      if (dd < 8) v0[dd] = hv; else v1[dd - 8] = hv;
    }
    char* base = (char*)xin;
    *(half8*)(base + ((m * 128 + q * 32) ^ ((m & 7) << 4))) = v0;
    *(half8*)(base + ((m * 128 + q * 32 + 16) ^ ((m & 7) << 4))) = v1;
  }

  stage_chunk(ws, 0, wbuf[0], t);
  __syncthreads();  // xin written + chunk 0 staged (syncthreads drains vmcnt)

  f32x4 acc[4][4];
  zero_acc(acc);

  // stage chunk c+1 into the other buffer, compute chunk c, barrier (drains stage).
#define CHUNK_STEP(c, bsrc, bstride, bkbase)                                   \
  {                                                                            \
    if ((c) + 1 < 14) stage_chunk(ws, (c) + 1, wbuf[((c) + 1) & 1], t);        \
    compute_chunk(acc, wbuf[(c) & 1], bsrc, bstride, bkbase, fg, pg, lr, lk);  \
    __syncthreads();                                                           \
  }

  // layer 0: xin (K=64)
  CHUNK_STEP(0, (const char*)xin, 128, 0);
  epilogue(acc, b0, (char*)hbuf, fg, pg, lr, lk);
  zero_acc(acc);
  __syncthreads();

  // layer 1: hbuf (K=256)
  CHUNK_STEP(1, (const char*)hbuf, 512, 0);
  CHUNK_STEP(2, (const char*)hbuf, 512, 128);
  CHUNK_STEP(3, (const char*)hbuf, 512, 256);
  CHUNK_STEP(4, (const char*)hbuf, 512, 384);
  epilogue(acc, b1, (char*)hbuf, fg, pg, lr, lk);
  zero_acc(acc);
  __syncthreads();

  // layer 2 (skip): hbuf (K=256) + xin (K=64)
  CHUNK_STEP(5, (const char*)hbuf, 512, 0);
  CHUNK_STEP(6, (const char*)hbuf, 512, 128);
  CHUNK_STEP(7, (const char*)hbuf, 512, 256);
  CHUNK_STEP(8, (const char*)hbuf, 512, 384);
  CHUNK_STEP(9, (const char*)xin, 128, 0);
  epilogue(acc, b2, (char*)hbuf, fg, pg, lr, lk);
  zero_acc(acc);
  __syncthreads();

  // layer 3: hbuf (K=256)
  CHUNK_STEP(10, (const char*)hbuf, 512, 0);
  CHUNK_STEP(11, (const char*)hbuf, 512, 128);
  CHUNK_STEP(12, (const char*)hbuf, 512, 256);
  CHUNK_STEP(13, (const char*)hbuf, 512, 384);
  epilogue(acc, b3, (char*)hbuf, fg, pg, lr, lk);
  __syncthreads();
#undef CHUNK_STEP

  // ---- heads: WH[16][256] @ h3 ; fg==0 waves cover all 128 points ----
  if (fg == 0) {
    f32x4 hacc[4];
#pragma unroll
    for (int mt = 0; mt < 4; ++mt) {
      f32x4 z = {0.f, 0.f, 0.f, 0.f};
      hacc[mt] = z;
    }
    const short* WH = ws + WH_OFF;
#pragma unroll
    for (int ks = 0; ks < 8; ++ks) {
      const half8 ah = *(const half8*)(WH + lr * 256 + ks * 32 + lk * 8);
#pragma unroll
      for (int mt = 0; mt < 4; ++mt) {
        const int m = pg * 64 + mt * 16 + lr;
        const half8 bh = *(const half8*)((const char*)hbuf +
                                         ((m * 512 + ks * 64 + lk * 16) ^ ((m & 7) << 4)));
        hacc[mt] = __builtin_amdgcn_mfma_f32_16x16x32_f16(ah, bh, hacc[mt], 0, 0, 0);
      }
    }
    float hb[4];
#pragma unroll
    for (int r = 0; r < 4; ++r) {
      const int j = lk * 4 + r;
      hb[r] = (j < 3) ? bxyz[j] : (j < 7) ? brot[j - 3] : (j < 10) ? bscale[j - 7]
              : (j == 10) ? bop[0] : 0.f;
    }
#pragma unroll
    for (int mt = 0; mt < 4; ++mt) {
      const int p = p0 + pg * 64 + mt * 16 + lr;
#pragma unroll
      for (int r = 0; r < 4; ++r) {
        const int j = lk * 4 + r;
        const float v = hacc[mt][r] + hb[r];
        if (j < 3)        out[p * 3 + j] = v;
        else if (j < 7)   out[3 * NPTS + p * 4 + (j - 3)] = v;
        else if (j < 10)  out[7 * NPTS + p * 3 + (j - 7)] = v;
        else if (j == 10) out[10 * NPTS + p] = v;
      }
    }
  }
}

extern "C" void kernel_launch(void* const* d_in, const int* in_sizes, int n_in,
                              void* d_out, int out_size, void* d_ws, size_t ws_size,
                              hipStream_t stream) {
  const float* xyz    = (const float*)d_in[0];
  const float* tptr   = (const float*)d_in[1];
  const float* W0     = (const float*)d_in[2];
  const float* b0     = (const float*)d_in[3];
  const float* W1     = (const float*)d_in[4];
  const float* b1     = (const float*)d_in[5];
  const float* W2     = (const float*)d_in[6];
  const float* b2     = (const float*)d_in[7];
  const float* W3     = (const float*)d_in[8];
  const float* b3     = (const float*)d_in[9];
  const float* Wxyz   = (const float*)d_in[10];
  const float* bxyz   = (const float*)d_in[11];
  const float* Wrot   = (const float*)d_in[12];
  const float* brot   = (const float*)d_in[13];
  const float* Wscale = (const float*)d_in[14];
  const float* bscale = (const float*)d_in[15];
  const float* Wop    = (const float*)d_in[16];
  const float* bop    = (const float*)d_in[17];
  short* ws  = (short*)d_ws;
  float* out = (float*)d_out;

  prep_kernel<<<256, 256, 0, stream>>>(W0, W1, W2, W3, Wxyz, Wrot, Wscale, Wop, ws);
  deform_kernel<<<NPTS / BM, NTHREADS, 0, stream>>>(xyz, tptr, b0, b1, b2, b3,
                                                    bxyz, brot, bscale, bop, ws, out);
}